// Round 19
// baseline (34.901 us; speedup 1.0000x reference)
//
#include <hip/hip_runtime.h>

// LDDMM variational evolve: N-body Gaussian kernel sums, N=8192, D=3, fp32.
// dmom_i = (1/SIG2) * sum_j K_ij * <mom_i,mom_j> * (pos_i - pos_j)
// dpos_i = sum_j K_ij * mom_j
// K_ij = exp(-||xi-xj||^2/(2*SIG2)), SIG2=0.01 -> exp2(-72.1348*d2)
//
// Cell list: K < 4e-6 for d2 > 0.25; dropped-pair error ~1e-2 << thr 2.36.
// Ladder: R13 24.9; R15 24.4; R18 flattened stream 23.9 (eval loop now
// proven NOT dominant: -25% pairs -> -0.5, -2.5x iters -> -0.5). Ledger
// says ~4.5us PER DISPATCH BOUNDARY (R13 -1 disp = -5; R16 +2 disp = +9).
// R19: TWO dispatches. D1 = fused single-block prep (LDS hist-with-rank +
// scan + scatter; R10 pattern). D2 = R18 main slimmed: i-data = 2 uniform
// 16B loads from sorted pm arrays (ci IS Pi.w), inv only for out address.
// R16/R17 lessons: global-atomic hist & spin grid-barriers are fatal.
// R7 NaN lesson: ci stays inside the exponent (arg <= 0 always).
// exp = __builtin_amdgcn_exp2f (plain exp2f -> OCML fixup; R2 measured).

#define NPTS  8192
#define NCXY  16
#define NCZ   32
#define NCELL (NCXY * NCXY * NCZ)   // 8192
#define ORIGIN    (-4.0f)
#define EDGE      0.5f
#define INV_EDGE  2.0f              // xy edge 0.5
#define INV_EDGEZ 4.0f              // z slab 0.25
#define RCUT2     0.25f

#define A_DOT 144.269504088896f     // 2*50*log2(e)
#define INV_ADOT (1.0f / 144.269504088896f)
#define A_R   (-72.134752044448f)   // -50*log2(e)
#define INV_SIG2 100.0f

#define EXP2(x) __builtin_amdgcn_exp2f(x)

__device__ __forceinline__ int clampi(int c, int hi) { return min(max(c, 0), hi); }

__device__ __forceinline__ int cell_of(float x, float y, float z) {
    const int cx = clampi((int)floorf((x - ORIGIN) * INV_EDGE),  NCXY - 1);
    const int cy = clampi((int)floorf((y - ORIGIN) * INV_EDGE),  NCXY - 1);
    const int cz = clampi((int)floorf((z - ORIGIN) * INV_EDGEZ), NCZ  - 1);
    return (cx * NCXY + cy) * NCZ + cz;
}

// ------ dispatch 1: fused prep -- LDS hist(+rank) + scan + scatter, 1 block ------
__global__ __launch_bounds__(1024)
void k_prep(const float* __restrict__ mom, const float* __restrict__ pos,
            int* __restrict__ start,
            float* __restrict__ pmP, float* __restrict__ pmM,
            int* __restrict__ inv)
{
    __shared__ int cnt[NCELL];      // 32 KB: counts -> exclusive starts
    __shared__ int wtot[16];
    __shared__ int wexcl[16];
    const int t = threadIdx.x;
    const int lane = t & 63;
    const int wid = t >> 6;

    #pragma unroll
    for (int k = 0; k < NCELL / 1024; ++k) cnt[t + k * 1024] = 0;
    __syncthreads();

    // phase 1: histogram with rank (atomicAdd returns old = within-cell rank)
    int cid[8], rnk[8];
    #pragma unroll
    for (int k = 0; k < 8; ++k) {
        const int i = t + k * 1024;
        cid[k] = cell_of(pos[3*i+0], pos[3*i+1], pos[3*i+2]);
        rnk[k] = atomicAdd(&cnt[cid[k]], 1);
    }
    __syncthreads();

    // phase 2: exclusive scan of 8192 bins (8 cells/thread + wave/block scan)
    int pre[8];
    int s = 0;
    #pragma unroll
    for (int k = 0; k < 8; ++k) { pre[k] = s; s += cnt[8*t + k]; }
    int p = s;
    #pragma unroll
    for (int off = 1; off < 64; off <<= 1) {
        const int v = __shfl_up(p, off);
        if (lane >= off) p += v;
    }
    if (lane == 63) wtot[wid] = p;
    __syncthreads();
    if (t < 16) {
        const int w = wtot[t];
        int q = w;
        #pragma unroll
        for (int off = 1; off < 16; off <<= 1) {
            const int v = __shfl_up(q, off);
            if (t >= off) q += v;
        }
        wexcl[t] = q - w;
    }
    __syncthreads();
    const int base = wexcl[wid] + (p - s);
    #pragma unroll
    for (int k = 0; k < 8; ++k) {
        const int v = base + pre[k];
        start[8*t + k] = v;
    }
    if (t == 0) start[NCELL] = NPTS;
    __syncthreads();
    #pragma unroll
    for (int k = 0; k < 8; ++k) cnt[8*t + k] = base + pre[k];   // cnt := start
    __syncthreads();

    // phase 3: scatter packed records (dst = start[cell] + rank)
    #pragma unroll
    for (int k = 0; k < 8; ++k) {
        const int i = t + k * 1024;
        const int dst = cnt[cid[k]] + rnk[k];
        const float x = pos[3*i+0], y = pos[3*i+1], z = pos[3*i+2];
        const float r2 = x*x + y*y + z*z;
        reinterpret_cast<float4*>(pmP)[dst] =
            make_float4(A_DOT*x, A_DOT*y, A_DOT*z, A_R*r2);
        reinterpret_cast<float4*>(pmM)[dst] =
            make_float4(mom[3*i+0], mom[3*i+1], mom[3*i+2], 0.0f);
        inv[dst] = i;
    }
}

// ------- dispatch 2: main -- one wave per point, flattened virtual j-stream -------
__global__ __launch_bounds__(256)
void k_main(const float* __restrict__ pmP, const float* __restrict__ pmM,
            const int* __restrict__ inv, const int* __restrict__ start,
            float* __restrict__ out)
{
    const int wid  = (blockIdx.x * 256 + threadIdx.x) >> 6;   // sorted idx 0..8191
    const int lane = threadIdx.x & 63;

    const float4* __restrict__ pmPv = reinterpret_cast<const float4*>(pmP);
    const float4* __restrict__ pmMv = reinterpret_cast<const float4*>(pmM);

    // i-data: 2 uniform 16B loads from the SORTED arrays (ci = Pi.w).
    const float4 Pi = pmPv[wid];
    const float4 Mi = pmMv[wid];
    const float xi = Pi.x * INV_ADOT, yi = Pi.y * INV_ADOT, zi = Pi.z * INV_ADOT;
    const float pxi = Mi.x, pyi = Mi.y, pzi = Mi.z;
    const float ci  = Pi.w;

    const int cx = clampi((int)floorf((xi - ORIGIN) * INV_EDGE), NCXY - 1);
    const int cy = clampi((int)floorf((yi - ORIGIN) * INV_EDGE), NCXY - 1);

    // Lanes 0..8: fixed 3x3 columns, z-clipped range (st,len); pruned -> len 0.
    int st_l = 0, len_l = 0;
    if (lane < 9) {
        const int nx = cx + (lane / 3) - 1;
        const int ny = cy + (lane % 3) - 1;
        if (nx >= 0 && nx < NCXY && ny >= 0 && ny < NCXY) {
            const float X0 = ORIGIN + nx * EDGE;
            const float Y0 = ORIGIN + ny * EDGE;
            const float dx = fmaxf(fmaxf(X0 - xi, xi - (X0 + EDGE)), 0.0f);
            const float dy = fmaxf(fmaxf(Y0 - yi, yi - (Y0 + EDGE)), 0.0f);
            const float m2 = dx * dx + dy * dy;
            if (m2 <= RCUT2) {
                const float zr = __builtin_sqrtf(RCUT2 - m2);
                const int z0 = clampi((int)floorf((zi - zr - ORIGIN) * INV_EDGEZ), NCZ - 1);
                const int z1 = clampi((int)floorf((zi + zr - ORIGIN) * INV_EDGEZ), NCZ - 1);
                const int base = (nx * NCXY + ny) * NCZ;
                st_l  = start[base + z0];
                len_l = start[base + z1 + 1] - st_l;
            }
        }
    }

    // Inclusive prefix of len over lanes 0..8.
    int pref = len_l;
    #pragma unroll
    for (int off = 1; off < 16; off <<= 1) {
        const int v = __shfl_up(pref, off);
        if (lane >= off) pref += v;
    }
    const int T = __shfl(pref, 8);    // total virtual stream length

    // Wave-uniform tables: p0[q] = exclusive prefix, ofs[q] = st - p0.
    int p0[9], ofs[9];
    #pragma unroll
    for (int q = 0; q < 9; ++q) {
        const int pr = __shfl(pref, q);
        const int ln = __shfl(len_l, q);
        const int st = __shfl(st_l, q);
        p0[q]  = pr - ln;
        ofs[q] = st - (pr - ln);
    }

    float S = 0.f, SPx = 0.f, SPy = 0.f, SPz = 0.f;
    float apx = 0.f, apy = 0.f, apz = 0.f;

    for (int f0 = 0; f0 < T; f0 += 64) {
        const int f = f0 + lane;
        // column select: largest q with p0[q] <= f
        int off_sel = ofs[0];
        #pragma unroll
        for (int q = 1; q < 9; ++q)
            off_sel = (f >= p0[q]) ? ofs[q] : off_sel;
        if (f < T) {
            const int j = f + off_sel;
            const float4 P = pmPv[j];     // segmented-coalesced
            const float4 M = pmMv[j];
            // arg = ci + A_DOT*<xi,xj> + A_R*rj2 = -72.13*d2 <= 0 (no overflow)
            float arg = __builtin_fmaf(zi, P.z, ci + P.w);
            arg = __builtin_fmaf(yi, P.y, arg);
            arg = __builtin_fmaf(xi, P.x, arg);
            const float K = EXP2(arg);
            const float C = __builtin_fmaf(pzi, M.z,
                              __builtin_fmaf(pyi, M.y, pxi * M.x));
            const float s = K * C;
            S += s;
            SPx = __builtin_fmaf(s, P.x, SPx);
            SPy = __builtin_fmaf(s, P.y, SPy);
            SPz = __builtin_fmaf(s, P.z, SPz);
            apx = __builtin_fmaf(K, M.x, apx);
            apy = __builtin_fmaf(K, M.y, apy);
            apz = __builtin_fmaf(K, M.z, apz);
        }
    }

    // 64-lane butterfly reduce of the 7 accumulators.
    #pragma unroll
    for (int off = 1; off < 64; off <<= 1) {
        S   += __shfl_xor(S,   off);
        SPx += __shfl_xor(SPx, off);
        SPy += __shfl_xor(SPy, off);
        SPz += __shfl_xor(SPz, off);
        apx += __shfl_xor(apx, off);
        apy += __shfl_xor(apy, off);
        apz += __shfl_xor(apz, off);
    }

    if (lane == 0) {
        const int oi = inv[wid];      // original index, output addressing only
        const float us = INV_SIG2 / A_DOT;
        out[3*oi+0] = INV_SIG2 * xi * S - us * SPx;
        out[3*oi+1] = INV_SIG2 * yi * S - us * SPy;
        out[3*oi+2] = INV_SIG2 * zi * S - us * SPz;
        out[3*NPTS + 3*oi+0] = apx;
        out[3*NPTS + 3*oi+1] = apy;
        out[3*NPTS + 3*oi+2] = apz;
    }
}

extern "C" void kernel_launch(void* const* d_in, const int* in_sizes, int n_in,
                              void* d_out, int out_size, void* d_ws, size_t ws_size,
                              hipStream_t stream)
{
    const float* mom = (const float*)d_in[0];
    const float* pos = (const float*)d_in[1];
    float* out = (float*)d_out;

    // ws layout: pmP (4*NPTS f), pmM (4*NPTS f), inv (NPTS i), start (NCELL+1 i)
    float* pmP  = (float*)d_ws;
    float* pmM  = pmP + (size_t)4 * NPTS;
    int* inv    = (int*)(pmM + (size_t)4 * NPTS);
    int* start  = inv + NPTS;

    k_prep<<<1, 1024, 0, stream>>>(mom, pos, start, pmP, pmM, inv);
    k_main<<<(NPTS * 64) / 256, 256, 0, stream>>>(pmP, pmM, inv, start, out);
}

// Round 20
// 27.766 us; speedup vs baseline: 1.2570x; 1.2570x over previous
//
#include <hip/hip_runtime.h>

// LDDMM variational evolve: N-body Gaussian kernel sums, N=8192, D=3, fp32.
// dmom_i = (1/SIG2) * sum_j K_ij * <mom_i,mom_j> * (pos_i - pos_j)
// dpos_i = sum_j K_ij * mom_j
// K_ij = exp(-||xi-xj||^2/(2*SIG2)), SIG2=0.01 -> exp2(-72.1348*d2)
//
// Cell list: K < 4e-6 for d2 > 0.25; dropped-pair error ~1e-2 << thr 2.36.
// Ladder: R13 24.9; R15 24.4; R18 23.9; R19 fused 1-block prep REGRESSED
// 34.9 (single-CU scatter ~ +10us; boundary tax is only ~1us -> main ~12-15
// is the real target). R20: (1) 32-LANE GROUPS, 2 points/wave: butterfly
// 6->5 steps at half the waves (-58% LDS-pipe shuffle traffic), setup
// amortizes x2, ceil(T/32) quantization; (2) STRIDED wave->point map
// v=((w&255)<<4)|(w>>8) so each CU samples dense+sparse points (sorted
// order clusters the Gaussian core into few blocks = CU imbalance).
// Prep = R18's proven countscan + scatter (single-variable on main).
// R16/R17 lessons: global-atomic hist & spin grid-barriers are fatal.
// R7 NaN lesson: ci stays inside the exponent (arg <= 0 always).
// exp = __builtin_amdgcn_exp2f (plain exp2f -> OCML fixup; R2 measured).

#define NPTS  8192
#define NCXY  16
#define NCZ   32
#define NCELL (NCXY * NCXY * NCZ)   // 8192
#define ORIGIN    (-4.0f)
#define EDGE      0.5f
#define INV_EDGE  2.0f              // xy edge 0.5
#define INV_EDGEZ 4.0f              // z slab 0.25
#define RCUT2     0.25f

#define A_DOT 144.269504088896f     // 2*50*log2(e)
#define INV_ADOT (1.0f / 144.269504088896f)
#define A_R   (-72.134752044448f)   // -50*log2(e)
#define INV_SIG2 100.0f

#define EXP2(x) __builtin_amdgcn_exp2f(x)

__device__ __forceinline__ int clampi(int c, int hi) { return min(max(c, 0), hi); }

__device__ __forceinline__ int cell_of(float x, float y, float z) {
    const int cx = clampi((int)floorf((x - ORIGIN) * INV_EDGE),  NCXY - 1);
    const int cy = clampi((int)floorf((y - ORIGIN) * INV_EDGE),  NCXY - 1);
    const int cz = clampi((int)floorf((z - ORIGIN) * INV_EDGEZ), NCZ  - 1);
    return (cx * NCXY + cy) * NCZ + cz;
}

// ---------------- prep 1: count (LDS hist) + scan, one block ----------------
__global__ __launch_bounds__(1024)
void k_countscan(const float* __restrict__ pos,
                 int* __restrict__ start, int* __restrict__ cur)
{
    __shared__ int cnt[NCELL];      // 32 KB
    __shared__ int wtot[16];
    __shared__ int wexcl[16];
    const int t = threadIdx.x;
    const int lane = t & 63;
    const int wid = t >> 6;

    #pragma unroll
    for (int k = 0; k < NCELL / 1024; ++k) cnt[t + k * 1024] = 0;
    __syncthreads();

    #pragma unroll
    for (int k = 0; k < NPTS / 1024; ++k) {
        const int i = t + k * 1024;
        atomicAdd(&cnt[cell_of(pos[3*i+0], pos[3*i+1], pos[3*i+2])], 1);
    }
    __syncthreads();

    // scan 8192 bins: thread t owns cells 8t..8t+7
    int pre[8];
    int s = 0;
    #pragma unroll
    for (int k = 0; k < 8; ++k) { pre[k] = s; s += cnt[8*t + k]; }
    int p = s;
    #pragma unroll
    for (int off = 1; off < 64; off <<= 1) {
        const int v = __shfl_up(p, off);
        if (lane >= off) p += v;
    }
    if (lane == 63) wtot[wid] = p;
    __syncthreads();
    if (t < 16) {
        const int w = wtot[t];
        int q = w;
        #pragma unroll
        for (int off = 1; off < 16; off <<= 1) {
            const int v = __shfl_up(q, off);
            if (t >= off) q += v;
        }
        wexcl[t] = q - w;
    }
    __syncthreads();
    const int base = wexcl[wid] + (p - s);
    #pragma unroll
    for (int k = 0; k < 8; ++k) {
        const int v = base + pre[k];
        start[8*t + k] = v;
        cur[8*t + k] = v;
    }
    if (t == 0) start[NCELL] = NPTS;
}

// ---------------- prep 2: scatter (parallel, atomic cursor ranks) ----------------
__global__ __launch_bounds__(256)
void k_scatter(const float* __restrict__ mom, const float* __restrict__ pos,
               int* __restrict__ cur,
               float* __restrict__ pmP, float* __restrict__ pmM,
               int* __restrict__ inv)
{
    const int i = blockIdx.x * 256 + threadIdx.x;
    const float x = pos[3*i+0], y = pos[3*i+1], z = pos[3*i+2];
    const int dst = atomicAdd(&cur[cell_of(x, y, z)], 1);
    const float r2 = x*x + y*y + z*z;
    reinterpret_cast<float4*>(pmP)[dst] = make_float4(A_DOT*x, A_DOT*y, A_DOT*z, A_R*r2);
    reinterpret_cast<float4*>(pmM)[dst] = make_float4(mom[3*i+0], mom[3*i+1], mom[3*i+2], 0.0f);
    inv[dst] = i;
}

// ---- main: 32-lane group per point (2 pts/wave), flattened virtual j-stream ----
__global__ __launch_bounds__(256)
void k_main(const float* __restrict__ pmP, const float* __restrict__ pmM,
            const int* __restrict__ inv, const int* __restrict__ start,
            float* __restrict__ out)
{
    const int w     = (blockIdx.x * 256 + threadIdx.x) >> 6;  // wave 0..4095
    const int lane  = threadIdx.x & 63;
    const int glane = lane & 31;                              // lane in group
    const int grp   = lane >> 5;                              // 0 or 1

    // Strided wave->pair map (bijective): spread dense core across CUs.
    const int v  = ((w & 255) << 4) | (w >> 8);               // 0..4095
    const int si = 2 * v + grp;                               // sorted point idx

    const float4* __restrict__ pmPv = reinterpret_cast<const float4*>(pmP);
    const float4* __restrict__ pmMv = reinterpret_cast<const float4*>(pmM);

    // i-data: group-uniform 16B loads from sorted arrays (ci = Pi.w).
    const float4 Pi = pmPv[si];
    const float4 Mi = pmMv[si];
    const float xi = Pi.x * INV_ADOT, yi = Pi.y * INV_ADOT, zi = Pi.z * INV_ADOT;
    const float pxi = Mi.x, pyi = Mi.y, pzi = Mi.z;
    const float ci  = Pi.w;

    const int cx = clampi((int)floorf((xi - ORIGIN) * INV_EDGE), NCXY - 1);
    const int cy = clampi((int)floorf((yi - ORIGIN) * INV_EDGE), NCXY - 1);

    // glane 0..8: fixed 3x3 columns, z-clipped range (st,len); pruned -> len 0.
    int st_l = 0, len_l = 0;
    if (glane < 9) {
        const int nx = cx + (glane / 3) - 1;
        const int ny = cy + (glane % 3) - 1;
        if (nx >= 0 && nx < NCXY && ny >= 0 && ny < NCXY) {
            const float X0 = ORIGIN + nx * EDGE;
            const float Y0 = ORIGIN + ny * EDGE;
            const float dx = fmaxf(fmaxf(X0 - xi, xi - (X0 + EDGE)), 0.0f);
            const float dy = fmaxf(fmaxf(Y0 - yi, yi - (Y0 + EDGE)), 0.0f);
            const float m2 = dx * dx + dy * dy;
            if (m2 <= RCUT2) {
                const float zr = __builtin_sqrtf(RCUT2 - m2);
                const int z0 = clampi((int)floorf((zi - zr - ORIGIN) * INV_EDGEZ), NCZ - 1);
                const int z1 = clampi((int)floorf((zi + zr - ORIGIN) * INV_EDGEZ), NCZ - 1);
                const int base = (nx * NCXY + ny) * NCZ;
                st_l  = start[base + z0];
                len_l = start[base + z1 + 1] - st_l;
            }
        }
    }

    // Group-local inclusive prefix of len over glane 0..8 (off<=8 < 32: safe).
    int pref = len_l;
    #pragma unroll
    for (int off = 1; off < 16; off <<= 1) {
        const int vv = __shfl_up(pref, off);
        if (glane >= off) pref += vv;
    }
    const int gbase = lane & 32;                 // group base lane
    const int T = __shfl(pref, gbase + 8);       // group stream length
    const int Tmax = max(__shfl(pref, 8), __shfl(pref, 40));   // wave-uniform

    // Group-uniform tables: p0[q] = exclusive prefix, ofs[q] = st - p0.
    int p0[9], ofs[9];
    #pragma unroll
    for (int q = 0; q < 9; ++q) {
        const int pr = __shfl(pref, gbase + q);
        const int ln = __shfl(len_l, gbase + q);
        const int st = __shfl(st_l, gbase + q);
        p0[q]  = pr - ln;
        ofs[q] = st - (pr - ln);
    }

    float S = 0.f, SPx = 0.f, SPy = 0.f, SPz = 0.f;
    float apx = 0.f, apy = 0.f, apz = 0.f;

    for (int f0 = 0; f0 < Tmax; f0 += 32) {
        const int f = f0 + glane;
        // column select: largest q with p0[q] <= f
        int off_sel = ofs[0];
        #pragma unroll
        for (int q = 1; q < 9; ++q)
            off_sel = (f >= p0[q]) ? ofs[q] : off_sel;
        if (f < T) {
            const int j = f + off_sel;
            const float4 P = pmPv[j];     // segmented-coalesced
            const float4 M = pmMv[j];
            // arg = ci + A_DOT*<xi,xj> + A_R*rj2 = -72.13*d2 <= 0 (no overflow)
            float arg = __builtin_fmaf(zi, P.z, ci + P.w);
            arg = __builtin_fmaf(yi, P.y, arg);
            arg = __builtin_fmaf(xi, P.x, arg);
            const float K = EXP2(arg);
            const float C = __builtin_fmaf(pzi, M.z,
                              __builtin_fmaf(pyi, M.y, pxi * M.x));
            const float s = K * C;
            S += s;
            SPx = __builtin_fmaf(s, P.x, SPx);
            SPy = __builtin_fmaf(s, P.y, SPy);
            SPz = __builtin_fmaf(s, P.z, SPz);
            apx = __builtin_fmaf(K, M.x, apx);
            apy = __builtin_fmaf(K, M.y, apy);
            apz = __builtin_fmaf(K, M.z, apz);
        }
    }

    // 5-step butterfly within the 32-lane group (xor keeps bit 5).
    #pragma unroll
    for (int off = 1; off < 32; off <<= 1) {
        S   += __shfl_xor(S,   off);
        SPx += __shfl_xor(SPx, off);
        SPy += __shfl_xor(SPy, off);
        SPz += __shfl_xor(SPz, off);
        apx += __shfl_xor(apx, off);
        apy += __shfl_xor(apy, off);
        apz += __shfl_xor(apz, off);
    }

    if (glane == 0) {
        const int oi = inv[si];       // original index, output addressing only
        const float us = INV_SIG2 / A_DOT;
        out[3*oi+0] = INV_SIG2 * xi * S - us * SPx;
        out[3*oi+1] = INV_SIG2 * yi * S - us * SPy;
        out[3*oi+2] = INV_SIG2 * zi * S - us * SPz;
        out[3*NPTS + 3*oi+0] = apx;
        out[3*NPTS + 3*oi+1] = apy;
        out[3*NPTS + 3*oi+2] = apz;
    }
}

extern "C" void kernel_launch(void* const* d_in, const int* in_sizes, int n_in,
                              void* d_out, int out_size, void* d_ws, size_t ws_size,
                              hipStream_t stream)
{
    const float* mom = (const float*)d_in[0];
    const float* pos = (const float*)d_in[1];
    float* out = (float*)d_out;

    // ws layout: pmP (4*NPTS f), pmM (4*NPTS f), inv (NPTS i),
    //            start (NCELL+1 i), cur (NCELL i)  -> ~355 KB
    float* pmP  = (float*)d_ws;
    float* pmM  = pmP + (size_t)4 * NPTS;
    int* inv    = (int*)(pmM + (size_t)4 * NPTS);
    int* start  = inv + NPTS;
    int* cur    = start + NCELL + 1;

    k_countscan<<<1, 1024, 0, stream>>>(pos, start, cur);
    k_scatter<<<NPTS / 256, 256, 0, stream>>>(mom, pos, cur, pmP, pmM, inv);
    // 4096 waves = 1024 blocks x 4 waves (4 blocks/CU, 4 waves/SIMD)
    k_main<<<1024, 256, 0, stream>>>(pmP, pmM, inv, start, out);
}

// Round 21
// 23.917 us; speedup vs baseline: 1.4593x; 1.1609x over previous
//
#include <hip/hip_runtime.h>

// LDDMM variational evolve: N-body Gaussian kernel sums, N=8192, D=3, fp32.
// dmom_i = (1/SIG2) * sum_j K_ij * <mom_i,mom_j> * (pos_i - pos_j)
// dpos_i = sum_j K_ij * mom_j
// K_ij = exp(-||xi-xj||^2/(2*SIG2)), SIG2=0.01 -> exp2(-72.1348*d2)
//
// Cell list: K < 4e-6 for d2 > 0.25; dropped-pair error ~1e-2 << thr 2.36.
// Ladder: R13 24.9; R15 24.4; R18 23.9 (best); R19 fused prep +11 (single-CU
// scatter); R20 strided+32lane +3.9 (killed L1 locality AND halved occupancy
// -> main NEEDS sorted-adjacent waves + 32 waves/CU). R21: (1) main in
// 64-thread blocks (same grid/order/occupancy, decoupled per-wave block
// retirement -- variable-T waves no longer hold 3 siblings' resources);
// (2) countscan histogram reads points as 6xfloat4 per thread (1/3 the
// load-issues in the one phase that runs on a single CU).
// R16/R17 lessons: global-atomic hist & spin grid-barriers are fatal.
// R7 NaN lesson: ci stays inside the exponent (arg <= 0 always).
// exp = __builtin_amdgcn_exp2f (plain exp2f -> OCML fixup; R2 measured).

#define NPTS  8192
#define NCXY  16
#define NCZ   32
#define NCELL (NCXY * NCXY * NCZ)   // 8192
#define ORIGIN    (-4.0f)
#define EDGE      0.5f
#define INV_EDGE  2.0f              // xy edge 0.5
#define INV_EDGEZ 4.0f              // z slab 0.25
#define RCUT2     0.25f

#define A_DOT 144.269504088896f     // 2*50*log2(e)
#define INV_ADOT (1.0f / 144.269504088896f)
#define A_R   (-72.134752044448f)   // -50*log2(e)
#define INV_SIG2 100.0f

#define EXP2(x) __builtin_amdgcn_exp2f(x)

__device__ __forceinline__ int clampi(int c, int hi) { return min(max(c, 0), hi); }

__device__ __forceinline__ int cell_of(float x, float y, float z) {
    const int cx = clampi((int)floorf((x - ORIGIN) * INV_EDGE),  NCXY - 1);
    const int cy = clampi((int)floorf((y - ORIGIN) * INV_EDGE),  NCXY - 1);
    const int cz = clampi((int)floorf((z - ORIGIN) * INV_EDGEZ), NCZ  - 1);
    return (cx * NCXY + cy) * NCZ + cz;
}

// ---------------- prep 1: count (LDS hist, vec loads) + scan, one block ----------------
__global__ __launch_bounds__(1024)
void k_countscan(const float* __restrict__ pos,
                 int* __restrict__ start, int* __restrict__ cur)
{
    __shared__ int cnt[NCELL];      // 32 KB
    __shared__ int wtot[16];
    __shared__ int wexcl[16];
    const int t = threadIdx.x;
    const int lane = t & 63;
    const int wid = t >> 6;

    #pragma unroll
    for (int k = 0; k < NCELL / 1024; ++k) cnt[t + k * 1024] = 0;
    __syncthreads();

    // histogram: thread t owns points 8t..8t+7, read as 6 x float4 (96 B)
    {
        const float4* pv = reinterpret_cast<const float4*>(pos) + 6 * t;
        float4 v0 = pv[0], v1 = pv[1], v2 = pv[2];
        float4 v3 = pv[3], v4 = pv[4], v5 = pv[5];
        const float px[8] = {v0.x, v0.w, v1.z, v2.y, v3.x, v3.w, v4.z, v5.y};
        const float py[8] = {v0.y, v1.x, v1.w, v2.z, v3.y, v4.x, v4.w, v5.z};
        const float pz[8] = {v0.z, v1.y, v2.x, v2.w, v3.z, v4.y, v5.x, v5.w};
        #pragma unroll
        for (int k = 0; k < 8; ++k)
            atomicAdd(&cnt[cell_of(px[k], py[k], pz[k])], 1);
    }
    __syncthreads();

    // scan 8192 bins: thread t owns cells 8t..8t+7
    int pre[8];
    int s = 0;
    #pragma unroll
    for (int k = 0; k < 8; ++k) { pre[k] = s; s += cnt[8*t + k]; }
    int p = s;
    #pragma unroll
    for (int off = 1; off < 64; off <<= 1) {
        const int v = __shfl_up(p, off);
        if (lane >= off) p += v;
    }
    if (lane == 63) wtot[wid] = p;
    __syncthreads();
    if (t < 16) {
        const int w = wtot[t];
        int q = w;
        #pragma unroll
        for (int off = 1; off < 16; off <<= 1) {
            const int v = __shfl_up(q, off);
            if (t >= off) q += v;
        }
        wexcl[t] = q - w;
    }
    __syncthreads();
    const int base = wexcl[wid] + (p - s);
    #pragma unroll
    for (int k = 0; k < 8; ++k) {
        const int v = base + pre[k];
        start[8*t + k] = v;
        cur[8*t + k] = v;
    }
    if (t == 0) start[NCELL] = NPTS;
}

// ---------------- prep 2: scatter (parallel, atomic cursor ranks) ----------------
__global__ __launch_bounds__(256)
void k_scatter(const float* __restrict__ mom, const float* __restrict__ pos,
               int* __restrict__ cur,
               float* __restrict__ pmP, float* __restrict__ pmM,
               int* __restrict__ inv)
{
    const int i = blockIdx.x * 256 + threadIdx.x;
    const float x = pos[3*i+0], y = pos[3*i+1], z = pos[3*i+2];
    const int dst = atomicAdd(&cur[cell_of(x, y, z)], 1);
    const float r2 = x*x + y*y + z*z;
    reinterpret_cast<float4*>(pmP)[dst] = make_float4(A_DOT*x, A_DOT*y, A_DOT*z, A_R*r2);
    reinterpret_cast<float4*>(pmM)[dst] = make_float4(mom[3*i+0], mom[3*i+1], mom[3*i+2], 0.0f);
    inv[dst] = i;
}

// ------- main: ONE WAVE PER BLOCK per point, flattened virtual j-stream -------
__global__ __launch_bounds__(64)
void k_main(const float* __restrict__ pmP, const float* __restrict__ pmM,
            const int* __restrict__ inv, const int* __restrict__ start,
            float* __restrict__ out)
{
    const int wid  = blockIdx.x;                              // sorted idx 0..8191
    const int lane = threadIdx.x;                             // 0..63

    const float4* __restrict__ pmPv = reinterpret_cast<const float4*>(pmP);
    const float4* __restrict__ pmMv = reinterpret_cast<const float4*>(pmM);

    // i-data: 2 uniform 16B loads from the SORTED arrays (ci = Pi.w).
    const float4 Pi = pmPv[wid];
    const float4 Mi = pmMv[wid];
    const float xi = Pi.x * INV_ADOT, yi = Pi.y * INV_ADOT, zi = Pi.z * INV_ADOT;
    const float pxi = Mi.x, pyi = Mi.y, pzi = Mi.z;
    const float ci  = Pi.w;

    const int cx = clampi((int)floorf((xi - ORIGIN) * INV_EDGE), NCXY - 1);
    const int cy = clampi((int)floorf((yi - ORIGIN) * INV_EDGE), NCXY - 1);

    // Lanes 0..8: fixed 3x3 columns, z-clipped range (st,len); pruned -> len 0.
    int st_l = 0, len_l = 0;
    if (lane < 9) {
        const int nx = cx + (lane / 3) - 1;
        const int ny = cy + (lane % 3) - 1;
        if (nx >= 0 && nx < NCXY && ny >= 0 && ny < NCXY) {
            const float X0 = ORIGIN + nx * EDGE;
            const float Y0 = ORIGIN + ny * EDGE;
            const float dx = fmaxf(fmaxf(X0 - xi, xi - (X0 + EDGE)), 0.0f);
            const float dy = fmaxf(fmaxf(Y0 - yi, yi - (Y0 + EDGE)), 0.0f);
            const float m2 = dx * dx + dy * dy;
            if (m2 <= RCUT2) {
                const float zr = __builtin_sqrtf(RCUT2 - m2);
                const int z0 = clampi((int)floorf((zi - zr - ORIGIN) * INV_EDGEZ), NCZ - 1);
                const int z1 = clampi((int)floorf((zi + zr - ORIGIN) * INV_EDGEZ), NCZ - 1);
                const int base = (nx * NCXY + ny) * NCZ;
                st_l  = start[base + z0];
                len_l = start[base + z1 + 1] - st_l;
            }
        }
    }

    // Inclusive prefix of len over lanes 0..8.
    int pref = len_l;
    #pragma unroll
    for (int off = 1; off < 16; off <<= 1) {
        const int v = __shfl_up(pref, off);
        if (lane >= off) pref += v;
    }
    const int T = __shfl(pref, 8);    // total virtual stream length

    // Wave-uniform tables: p0[q] = exclusive prefix, ofs[q] = st - p0.
    int p0[9], ofs[9];
    #pragma unroll
    for (int q = 0; q < 9; ++q) {
        const int pr = __shfl(pref, q);
        const int ln = __shfl(len_l, q);
        const int st = __shfl(st_l, q);
        p0[q]  = pr - ln;
        ofs[q] = st - (pr - ln);
    }

    float S = 0.f, SPx = 0.f, SPy = 0.f, SPz = 0.f;
    float apx = 0.f, apy = 0.f, apz = 0.f;

    for (int f0 = 0; f0 < T; f0 += 64) {
        const int f = f0 + lane;
        // column select: largest q with p0[q] <= f
        int off_sel = ofs[0];
        #pragma unroll
        for (int q = 1; q < 9; ++q)
            off_sel = (f >= p0[q]) ? ofs[q] : off_sel;
        if (f < T) {
            const int j = f + off_sel;
            const float4 P = pmPv[j];     // segmented-coalesced
            const float4 M = pmMv[j];
            // arg = ci + A_DOT*<xi,xj> + A_R*rj2 = -72.13*d2 <= 0 (no overflow)
            float arg = __builtin_fmaf(zi, P.z, ci + P.w);
            arg = __builtin_fmaf(yi, P.y, arg);
            arg = __builtin_fmaf(xi, P.x, arg);
            const float K = EXP2(arg);
            const float C = __builtin_fmaf(pzi, M.z,
                              __builtin_fmaf(pyi, M.y, pxi * M.x));
            const float s = K * C;
            S += s;
            SPx = __builtin_fmaf(s, P.x, SPx);
            SPy = __builtin_fmaf(s, P.y, SPy);
            SPz = __builtin_fmaf(s, P.z, SPz);
            apx = __builtin_fmaf(K, M.x, apx);
            apy = __builtin_fmaf(K, M.y, apy);
            apz = __builtin_fmaf(K, M.z, apz);
        }
    }

    // 64-lane butterfly reduce of the 7 accumulators.
    #pragma unroll
    for (int off = 1; off < 64; off <<= 1) {
        S   += __shfl_xor(S,   off);
        SPx += __shfl_xor(SPx, off);
        SPy += __shfl_xor(SPy, off);
        SPz += __shfl_xor(SPz, off);
        apx += __shfl_xor(apx, off);
        apy += __shfl_xor(apy, off);
        apz += __shfl_xor(apz, off);
    }

    if (lane == 0) {
        const int oi = inv[wid];      // original index, output addressing only
        const float us = INV_SIG2 / A_DOT;
        out[3*oi+0] = INV_SIG2 * xi * S - us * SPx;
        out[3*oi+1] = INV_SIG2 * yi * S - us * SPy;
        out[3*oi+2] = INV_SIG2 * zi * S - us * SPz;
        out[3*NPTS + 3*oi+0] = apx;
        out[3*NPTS + 3*oi+1] = apy;
        out[3*NPTS + 3*oi+2] = apz;
    }
}

extern "C" void kernel_launch(void* const* d_in, const int* in_sizes, int n_in,
                              void* d_out, int out_size, void* d_ws, size_t ws_size,
                              hipStream_t stream)
{
    const float* mom = (const float*)d_in[0];
    const float* pos = (const float*)d_in[1];
    float* out = (float*)d_out;

    // ws layout: pmP (4*NPTS f), pmM (4*NPTS f), inv (NPTS i),
    //            start (NCELL+1 i), cur (NCELL i)  -> ~355 KB
    float* pmP  = (float*)d_ws;
    float* pmM  = pmP + (size_t)4 * NPTS;
    int* inv    = (int*)(pmM + (size_t)4 * NPTS);
    int* start  = inv + NPTS;
    int* cur    = start + NCELL + 1;

    k_countscan<<<1, 1024, 0, stream>>>(pos, start, cur);
    k_scatter<<<NPTS / 256, 256, 0, stream>>>(mom, pos, cur, pmP, pmM, inv);
    k_main<<<NPTS, 64, 0, stream>>>(pmP, pmM, inv, start, out);
}